// Round 1
// baseline (199.292 us; speedup 1.0000x reference)
//
#include <hip/hip_runtime.h>
#include <hip/hip_bf16.h>
#include <math.h>

#define B_  4
#define R_  64
#define C_  192
#define WN_ 16

typedef __attribute__((ext_vector_type(8))) short short8;
typedef __attribute__((ext_vector_type(4))) float floatx4;

// round-to-nearest-even fp32 -> bf16 (as raw ushort)
static __device__ __forceinline__ unsigned short f2bf(float f) {
    union { float f; unsigned u; } v; v.f = f;
    unsigned r = v.u + 0x7fffu + ((v.u >> 16) & 1u);
    return (unsigned short)(r >> 16);
}

// ---------------------------------------------------------------------------
// Kernel 1: per-window pooled depthwise-conv mean, dotted with dc_w.
// pooled[b,win,c]*256 = sum_t k[t] * S_t, where S_t is the window sum clipped
// by the tap shift; S_t derived from full sum / edge rows / edge cols / corners.
// Writes w0[b*16+win] = sum_c pooled*dc_w  (dc_b added later).
// ---------------------------------------------------------------------------
__global__ void pool_kernel(const float* __restrict__ x,
                            const float* __restrict__ conv1_w,
                            const float* __restrict__ dc_w,
                            float* __restrict__ w0) {
    int blk = blockIdx.x;            // b*16 + win
    int b = blk >> 4, win = blk & 15;
    int wr = win >> 2, wc = win & 3;
    int c = threadIdx.x;             // 0..191
    const float* xb = x + ((size_t)b * 4096) * C_ + c;

    float Wsum = 0.f, Rtop = 0.f, Rbot = 0.f, Cleft = 0.f, Cright = 0.f;
    float c00 = 0.f, c0F = 0.f, cF0 = 0.f, cFF = 0.f;
    for (int ph = 0; ph < 16; ++ph) {
        int h = wr * 16 + ph;
        #pragma unroll
        for (int pw = 0; pw < 16; ++pw) {
            int w = wc * 16 + pw;
            float v = xb[((size_t)(h * 64 + w)) * C_];
            Wsum += v;
            if (ph == 0)  { Rtop += v; if (pw == 0) c00 = v; if (pw == 15) c0F = v; }
            if (ph == 15) { Rbot += v; if (pw == 0) cF0 = v; if (pw == 15) cFF = v; }
            if (pw == 0)  Cleft  += v;
            if (pw == 15) Cright += v;
        }
    }

    const float* kp = conv1_w + ((size_t)(win * C_ + c)) * 9;
    float pooled = 0.f;
    #pragma unroll
    for (int i = 0; i < 3; ++i) {
        #pragma unroll
        for (int j = 0; j < 3; ++j) {
            int di = i - 1, dj = j - 1;
            float S = Wsum;
            if (di == -1) S -= Rbot;   else if (di == 1) S -= Rtop;
            if (dj == -1) S -= Cright; else if (dj == 1) S -= Cleft;
            if (di == -1 && dj == -1) S += cFF;
            if (di == -1 && dj ==  1) S += cF0;
            if (di ==  1 && dj == -1) S += c0F;
            if (di ==  1 && dj ==  1) S += c00;
            pooled += kp[i * 3 + j] * S;
        }
    }

    float val = (pooled * (1.f / 256.f)) * dc_w[win * C_ + c];

    __shared__ float part[3];
    for (int off = 32; off; off >>= 1) val += __shfl_down(val, off, 64);
    int wv = threadIdx.x >> 6, lane = threadIdx.x & 63;
    if (lane == 0) part[wv] = val;
    __syncthreads();
    if (threadIdx.x == 0) w0[blk] = part[0] + part[1] + part[2];
}

// ---------------------------------------------------------------------------
// Kernel 2: tiny MLP -> sigmoid gates s[b,w]. One block, 64 threads.
// ---------------------------------------------------------------------------
__global__ void mlp_kernel(const float* __restrict__ w0,
                           const float* __restrict__ dc_b,
                           const float* __restrict__ l1_w,
                           const float* __restrict__ l1_b,
                           const float* __restrict__ l2_w,
                           const float* __restrict__ l2_b,
                           float* __restrict__ s_out) {
    __shared__ float hbuf[64];
    __shared__ float wb[16];
    int j = threadIdx.x;  // 0..63
    for (int b = 0; b < B_; ++b) {
        if (j < 16) wb[j] = w0[b * 16 + j] + dc_b[j];
        __syncthreads();
        float a = l1_b[j];
        #pragma unroll
        for (int w = 0; w < 16; ++w) a += wb[w] * l1_w[j * 16 + w];
        // exact gelu: 0.5*x*(1+erf(x/sqrt(2)))
        hbuf[j] = 0.5f * a * (1.f + erff(a * 0.70710678118654752f));
        __syncthreads();
        if (j < 16) {
            float a2 = l2_b[j];
            #pragma unroll
            for (int k = 0; k < 64; ++k) a2 += hbuf[k] * l2_w[j * 64 + k];
            s_out[b * 16 + j] = 1.f / (1.f + expf(-a2));
        }
        __syncthreads();
    }
}

// ---------------------------------------------------------------------------
// Kernel 3: effective dense conv weights, bf16, layout [b][tap][co][ci].
// W_eff = sum_w (fusion_w[co,w*C+ci] + fusion_w[co,16C+ci]*gk_w[w]) * s[b,w]
//               * conv1_w[w,ci,tap]  +  fusion_w[co,16C+ci]*gk_b
// ---------------------------------------------------------------------------
__global__ void weff_kernel(const float* __restrict__ conv1_w,
                            const float* __restrict__ gk_w,
                            const float* __restrict__ gk_b,
                            const float* __restrict__ fusion_w,
                            const float* __restrict__ s,
                            unsigned short* __restrict__ Wbf) {
    int blk = blockIdx.x;             // b*192 + co
    int b = blk / C_, co = blk % C_;
    int ci = threadIdx.x;             // 0..191
    float fg = fusion_w[(size_t)co * 3264 + 16 * C_ + ci];
    float acc[9];
    float g0 = fg * gk_b[0];
    #pragma unroll
    for (int t = 0; t < 9; ++t) acc[t] = g0;
    for (int w = 0; w < 16; ++w) {
        float coef = (fusion_w[(size_t)co * 3264 + w * C_ + ci] + fg * gk_w[w]) * s[b * 16 + w];
        const float* kp = conv1_w + ((size_t)(w * C_ + ci)) * 9;
        #pragma unroll
        for (int t = 0; t < 9; ++t) acc[t] += coef * kp[t];
    }
    #pragma unroll
    for (int t = 0; t < 9; ++t)
        Wbf[(((size_t)(b * 9 + t)) * C_ + co) * C_ + ci] = f2bf(acc[t]);
}

// ---------------------------------------------------------------------------
// Kernel 4: x (B,4096,192) fp32 -> zero-padded bf16 NHWC (B,66,66,192).
// Halo rows/cols are written as 0 so the conv needs no boundary predication.
// 4 pixels per 192-thread block; each thread converts 4 channels.
// ---------------------------------------------------------------------------
__global__ void xpad_kernel(const float* __restrict__ x,
                            unsigned short* __restrict__ xbf) {
    int t = threadIdx.x;                    // 0..191
    int pix = blockIdx.x * 4 + (t / 48);    // linear (b,hp,wp), < 4*66*66
    int cq = (t % 48) * 4;
    int b = pix / (66 * 66);
    int r = pix % (66 * 66);
    int hp = r / 66, wp = r % 66;
    int h = hp - 1, w = wp - 1;
    ushort4 o;
    if (h >= 0 && h < 64 && w >= 0 && w < 64) {
        const float4 v = *(const float4*)(x + (((size_t)b * 4096) + h * 64 + w) * C_ + cq);
        o.x = f2bf(v.x); o.y = f2bf(v.y); o.z = f2bf(v.z); o.w = f2bf(v.w);
    } else {
        o.x = o.y = o.z = o.w = 0;
    }
    *(ushort4*)(xbf + (size_t)pix * C_ + cq) = o;
}

// ---------------------------------------------------------------------------
// Kernel 5: dense 3x3 conv as implicit GEMM via MFMA.
// Block = one output row h (M=64 pixels) x 64 cout; 4 waves, each a 16x64
// strip (4 accumulators). K-loop = 9 taps x 6 chunks of K=32 over ci.
// A-frag: lane m=l&15 -> pixel, k=(l>>4)*8+j -> ci (16B contiguous load from
// padded bf16 x). B-frag: lane n=l&15 -> co row of Wbf[co][ci], same k (16B
// contiguous). C/D: col=lane&15 (co), row=(lane>>4)*4+reg (pixel).
// ---------------------------------------------------------------------------
__global__ __launch_bounds__(256) void conv_kernel(
        const unsigned short* __restrict__ xbf,
        const unsigned short* __restrict__ Wbf,
        const float* __restrict__ fusion_b,
        float* __restrict__ out) {
    int h  = blockIdx.x;          // 0..63
    int n0 = blockIdx.y * 64;     // 0,64,128
    int b  = blockIdx.z;          // 0..3
    int tid = threadIdx.x;
    int wv = tid >> 6;
    int lane = tid & 63;
    int lo = lane & 15, quad = lane >> 4;
    int mpix = wv * 16 + lo;      // this lane's A-row pixel (w coordinate)

    floatx4 acc[4];
    #pragma unroll
    for (int nt = 0; nt < 4; ++nt) acc[nt] = (floatx4){0.f, 0.f, 0.f, 0.f};

    const short* xp  = (const short*)xbf;
    const short* wpt = (const short*)Wbf;

    for (int t = 0; t < 9; ++t) {
        int dh = t / 3 - 1, dw = t % 3 - 1;
        const short* abase = xp +
            (((size_t)(b * 66 + h + dh + 1)) * 66 + (mpix + dw + 1)) * C_ + quad * 8;
        const short* bbase = wpt +
            (((size_t)(b * 9 + t)) * C_ + n0 + lo) * C_ + quad * 8;
        #pragma unroll
        for (int kc = 0; kc < 6; ++kc) {
            short8 af = *(const short8*)(abase + kc * 32);
            #pragma unroll
            for (int nt = 0; nt < 4; ++nt) {
                short8 bf8 = *(const short8*)(bbase + (size_t)nt * 16 * C_ + kc * 32);
                acc[nt] = __builtin_amdgcn_mfma_f32_16x16x32_bf16(af, bf8, acc[nt], 0, 0, 0);
            }
        }
    }

    #pragma unroll
    for (int nt = 0; nt < 4; ++nt) {
        int co = n0 + nt * 16 + lo;
        float fb = fusion_b[co];
        #pragma unroll
        for (int r = 0; r < 4; ++r) {
            int pw = wv * 16 + quad * 4 + r;   // pixel within the row
            out[(((size_t)b * 4096) + (size_t)h * 64 + pw) * C_ + co] = acc[nt][r] + fb;
        }
    }
}

// ---------------------------------------------------------------------------
extern "C" void kernel_launch(void* const* d_in, const int* in_sizes, int n_in,
                              void* d_out, int out_size, void* d_ws, size_t ws_size,
                              hipStream_t stream) {
    const float* x        = (const float*)d_in[0];
    const float* conv1_w  = (const float*)d_in[1];
    const float* dc_w     = (const float*)d_in[2];
    const float* dc_b     = (const float*)d_in[3];
    const float* l1_w     = (const float*)d_in[4];
    const float* l1_b     = (const float*)d_in[5];
    const float* l2_w     = (const float*)d_in[6];
    const float* l2_b     = (const float*)d_in[7];
    const float* gk_w     = (const float*)d_in[8];
    const float* gk_b     = (const float*)d_in[9];
    const float* fusion_w = (const float*)d_in[10];
    const float* fusion_b = (const float*)d_in[11];
    float* out = (float*)d_out;

    char* ws = (char*)d_ws;
    float* w0 = (float*)ws;                                   // 64 floats
    float* s  = w0 + 64;                                      // 64 floats
    unsigned short* Wbf = (unsigned short*)(ws + 512);        // 4*9*192*192 bf16 = 2,654,208 B
    unsigned short* xbf = (unsigned short*)(ws + 512 + 2654208); // 4*66*66*192 bf16 = 6,690,816 B
    // total ws use ~9.35 MB

    hipLaunchKernelGGL(pool_kernel, dim3(B_ * WN_), dim3(C_), 0, stream, x, conv1_w, dc_w, w0);
    hipLaunchKernelGGL(mlp_kernel, dim3(1), dim3(64), 0, stream, w0, dc_b, l1_w, l1_b, l2_w, l2_b, s);
    hipLaunchKernelGGL(weff_kernel, dim3(B_ * C_), dim3(C_), 0, stream, conv1_w, gk_w, gk_b, fusion_w, s, Wbf);
    hipLaunchKernelGGL(xpad_kernel, dim3(4 * 66 * 66 / 4), dim3(C_), 0, stream, x, xbf);
    hipLaunchKernelGGL(conv_kernel, dim3(R_, 3, B_), dim3(256), 0, stream, xbf, Wbf, fusion_b, out);
}

// Round 2
// 153.102 us; speedup vs baseline: 1.3017x; 1.3017x over previous
//
#include <hip/hip_runtime.h>
#include <hip/hip_bf16.h>
#include <math.h>

#define B_  4
#define R_  64
#define C_  192
#define WN_ 16

typedef __attribute__((ext_vector_type(8))) short short8;
typedef __attribute__((ext_vector_type(4))) float floatx4;

// round-to-nearest-even fp32 -> bf16 (as raw ushort)
static __device__ __forceinline__ unsigned short f2bf(float f) {
    union { float f; unsigned u; } v; v.f = f;
    unsigned r = v.u + 0x7fffu + ((v.u >> 16) & 1u);
    return (unsigned short)(r >> 16);
}

// ---------------------------------------------------------------------------
// Kernel 1: per-window pooled depthwise-conv mean, dotted with dc_w.
// ---------------------------------------------------------------------------
__global__ void pool_kernel(const float* __restrict__ x,
                            const float* __restrict__ conv1_w,
                            const float* __restrict__ dc_w,
                            float* __restrict__ w0) {
    int blk = blockIdx.x;            // b*16 + win
    int b = blk >> 4, win = blk & 15;
    int wr = win >> 2, wc = win & 3;
    int c = threadIdx.x;             // 0..191
    const float* xb = x + ((size_t)b * 4096) * C_ + c;

    float Wsum = 0.f, Rtop = 0.f, Rbot = 0.f, Cleft = 0.f, Cright = 0.f;
    float c00 = 0.f, c0F = 0.f, cF0 = 0.f, cFF = 0.f;
    #pragma unroll
    for (int ph = 0; ph < 16; ++ph) {
        int h = wr * 16 + ph;
        #pragma unroll
        for (int pw = 0; pw < 16; ++pw) {
            int w = wc * 16 + pw;
            float v = xb[((size_t)(h * 64 + w)) * C_];
            Wsum += v;
            if (ph == 0)  { Rtop += v; if (pw == 0) c00 = v; if (pw == 15) c0F = v; }
            if (ph == 15) { Rbot += v; if (pw == 0) cF0 = v; if (pw == 15) cFF = v; }
            if (pw == 0)  Cleft  += v;
            if (pw == 15) Cright += v;
        }
    }

    const float* kp = conv1_w + ((size_t)(win * C_ + c)) * 9;
    float pooled = 0.f;
    #pragma unroll
    for (int i = 0; i < 3; ++i) {
        #pragma unroll
        for (int j = 0; j < 3; ++j) {
            int di = i - 1, dj = j - 1;
            float S = Wsum;
            if (di == -1) S -= Rbot;   else if (di == 1) S -= Rtop;
            if (dj == -1) S -= Cright; else if (dj == 1) S -= Cleft;
            if (di == -1 && dj == -1) S += cFF;
            if (di == -1 && dj ==  1) S += cF0;
            if (di ==  1 && dj == -1) S += c0F;
            if (di ==  1 && dj ==  1) S += c00;
            pooled += kp[i * 3 + j] * S;
        }
    }

    float val = (pooled * (1.f / 256.f)) * dc_w[win * C_ + c];

    __shared__ float part[3];
    for (int off = 32; off; off >>= 1) val += __shfl_down(val, off, 64);
    int wv = threadIdx.x >> 6, lane = threadIdx.x & 63;
    if (lane == 0) part[wv] = val;
    __syncthreads();
    if (threadIdx.x == 0) w0[blk] = part[0] + part[1] + part[2];
}

// ---------------------------------------------------------------------------
// Kernel 2: tiny MLP -> sigmoid gates s[b,w]. One block, 64 threads.
// ---------------------------------------------------------------------------
__global__ void mlp_kernel(const float* __restrict__ w0,
                           const float* __restrict__ dc_b,
                           const float* __restrict__ l1_w,
                           const float* __restrict__ l1_b,
                           const float* __restrict__ l2_w,
                           const float* __restrict__ l2_b,
                           float* __restrict__ s_out) {
    __shared__ float hbuf[64];
    __shared__ float wb[16];
    int j = threadIdx.x;  // 0..63
    for (int b = 0; b < B_; ++b) {
        if (j < 16) wb[j] = w0[b * 16 + j] + dc_b[j];
        __syncthreads();
        float a = l1_b[j];
        #pragma unroll
        for (int w = 0; w < 16; ++w) a += wb[w] * l1_w[j * 16 + w];
        hbuf[j] = 0.5f * a * (1.f + erff(a * 0.70710678118654752f));
        __syncthreads();
        if (j < 16) {
            float a2 = l2_b[j];
            #pragma unroll
            for (int k = 0; k < 64; ++k) a2 += hbuf[k] * l2_w[j * 64 + k];
            s_out[b * 16 + j] = 1.f / (1.f + expf(-a2));
        }
        __syncthreads();
    }
}

// ---------------------------------------------------------------------------
// Kernel 3: effective dense conv weights, bf16, layout [b][tap][co][ci].
// ---------------------------------------------------------------------------
__global__ void weff_kernel(const float* __restrict__ conv1_w,
                            const float* __restrict__ gk_w,
                            const float* __restrict__ gk_b,
                            const float* __restrict__ fusion_w,
                            const float* __restrict__ s,
                            unsigned short* __restrict__ Wbf) {
    int blk = blockIdx.x;             // b*192 + co
    int b = blk / C_, co = blk % C_;
    int ci = threadIdx.x;             // 0..191
    float fg = fusion_w[(size_t)co * 3264 + 16 * C_ + ci];
    float acc[9];
    float g0 = fg * gk_b[0];
    #pragma unroll
    for (int t = 0; t < 9; ++t) acc[t] = g0;
    for (int w = 0; w < 16; ++w) {
        float coef = (fusion_w[(size_t)co * 3264 + w * C_ + ci] + fg * gk_w[w]) * s[b * 16 + w];
        const float* kp = conv1_w + ((size_t)(w * C_ + ci)) * 9;
        #pragma unroll
        for (int t = 0; t < 9; ++t) acc[t] += coef * kp[t];
    }
    #pragma unroll
    for (int t = 0; t < 9; ++t)
        Wbf[(((size_t)(b * 9 + t)) * C_ + co) * C_ + ci] = f2bf(acc[t]);
}

// ---------------------------------------------------------------------------
// Kernel 4: x (B,4096,192) fp32 -> zero-padded bf16 NHWC (B,66,66,192).
// ---------------------------------------------------------------------------
__global__ void xpad_kernel(const float* __restrict__ x,
                            unsigned short* __restrict__ xbf) {
    int t = threadIdx.x;                    // 0..191
    int pix = blockIdx.x * 4 + (t / 48);    // linear (b,hp,wp), < 4*66*66
    int cq = (t % 48) * 4;
    int b = pix / (66 * 66);
    int r = pix % (66 * 66);
    int hp = r / 66, wp = r % 66;
    int h = hp - 1, w = wp - 1;
    ushort4 o;
    if (h >= 0 && h < 64 && w >= 0 && w < 64) {
        const float4 v = *(const float4*)(x + (((size_t)b * 4096) + h * 64 + w) * C_ + cq);
        o.x = f2bf(v.x); o.y = f2bf(v.y); o.z = f2bf(v.z); o.w = f2bf(v.w);
    } else {
        o.x = o.y = o.z = o.w = 0;
    }
    *(ushort4*)(xbf + (size_t)pix * C_ + cq) = o;
}

// ---------------------------------------------------------------------------
// Kernel 5 (v2): dense 3x3 conv as register-tiled implicit GEMM.
// Block = one image row (64 px) x all 192 cout, one batch. 4 waves; wave wv
// owns cout slice [wv*48, wv*48+48) as 3 n-tiles; every wave spans all 64 px
// as 4 m-tiles -> 12 MFMAs per K-step from 4 A-frags + 3 B-frags (register
// reuse 1.7x; A-frags shared by all 4 waves -> L1 hits).
// K-loop = 9 taps x 6 ci-chunks of 32, fully unrolled, explicitly
// double-buffered: step i+1's 7 loads issue before step i's 12 MFMAs
// (structural prefetch ~58 cyc + compiler fine-grained vmcnt).
// ---------------------------------------------------------------------------
__global__ __launch_bounds__(256, 1) void conv_kernel(
        const unsigned short* __restrict__ xbf,
        const unsigned short* __restrict__ Wbf,
        const float* __restrict__ fusion_b,
        float* __restrict__ out) {
    const int h = blockIdx.x;     // 0..63
    const int b = blockIdx.y;     // 0..3
    const int tid = threadIdx.x;
    const int wv = tid >> 6;
    const int lane = tid & 63;
    const int lo = lane & 15, quad = lane >> 4;
    const int n0 = wv * 48;

    const short* xp = (const short*)xbf;
    const short* wp = (const short*)Wbf;

    int Abase[4], Bbase[3];
    #pragma unroll
    for (int mt = 0; mt < 4; ++mt)
        Abase[mt] = ((b * 66 + h + 1) * 66 + mt * 16 + lo + 1) * C_ + quad * 8;
    #pragma unroll
    for (int nt = 0; nt < 3; ++nt)
        Bbase[nt] = (b * 9 * C_ + n0 + nt * 16 + lo) * C_ + quad * 8;

    floatx4 acc[4][3];
    #pragma unroll
    for (int mt = 0; mt < 4; ++mt)
        #pragma unroll
        for (int nt = 0; nt < 3; ++nt)
            acc[mt][nt] = (floatx4){0.f, 0.f, 0.f, 0.f};

    short8 Abuf[2][4];
    short8 Bbuf[2][3];

    // preload step 0: tap 0 (dh=-1,dw=-1 -> offset (-66-1)*C_), kc 0
    #pragma unroll
    for (int mt = 0; mt < 4; ++mt)
        Abuf[0][mt] = *(const short8*)(xp + Abase[mt] - 67 * C_);
    #pragma unroll
    for (int nt = 0; nt < 3; ++nt)
        Bbuf[0][nt] = *(const short8*)(wp + Bbase[nt]);

    #pragma unroll
    for (int tap = 0; tap < 9; ++tap) {
        #pragma unroll
        for (int kc = 0; kc < 6; ++kc) {
            const int step = tap * 6 + kc;
            const int cur = step & 1, nxt = cur ^ 1;
            if (step < 53) {
                const int ntap = (kc == 5) ? tap + 1 : tap;
                const int nkc  = (kc == 5) ? 0 : kc + 1;
                const int ndh = ntap / 3 - 1, ndw = ntap % 3 - 1;
                const int aoff = (ndh * 66 + ndw) * C_ + nkc * 32;
                const int boff = ntap * (C_ * C_) + nkc * 32;
                #pragma unroll
                for (int mt = 0; mt < 4; ++mt)
                    Abuf[nxt][mt] = *(const short8*)(xp + Abase[mt] + aoff);
                #pragma unroll
                for (int nt = 0; nt < 3; ++nt)
                    Bbuf[nxt][nt] = *(const short8*)(wp + Bbase[nt] + boff);
            }
            #pragma unroll
            for (int mt = 0; mt < 4; ++mt)
                #pragma unroll
                for (int nt = 0; nt < 3; ++nt)
                    acc[mt][nt] = __builtin_amdgcn_mfma_f32_16x16x32_bf16(
                        Abuf[cur][mt], Bbuf[cur][nt], acc[mt][nt], 0, 0, 0);
        }
    }

    #pragma unroll
    for (int nt = 0; nt < 3; ++nt) {
        const int co = n0 + nt * 16 + lo;
        const float fb = fusion_b[co];
        #pragma unroll
        for (int mt = 0; mt < 4; ++mt) {
            #pragma unroll
            for (int r = 0; r < 4; ++r) {
                const int pix = mt * 16 + quad * 4 + r;
                out[(((size_t)b * 4096) + h * 64 + pix) * C_ + co] = acc[mt][nt][r] + fb;
            }
        }
    }
}

// ---------------------------------------------------------------------------
extern "C" void kernel_launch(void* const* d_in, const int* in_sizes, int n_in,
                              void* d_out, int out_size, void* d_ws, size_t ws_size,
                              hipStream_t stream) {
    const float* x        = (const float*)d_in[0];
    const float* conv1_w  = (const float*)d_in[1];
    const float* dc_w     = (const float*)d_in[2];
    const float* dc_b     = (const float*)d_in[3];
    const float* l1_w     = (const float*)d_in[4];
    const float* l1_b     = (const float*)d_in[5];
    const float* l2_w     = (const float*)d_in[6];
    const float* l2_b     = (const float*)d_in[7];
    const float* gk_w     = (const float*)d_in[8];
    const float* gk_b     = (const float*)d_in[9];
    const float* fusion_w = (const float*)d_in[10];
    const float* fusion_b = (const float*)d_in[11];
    float* out = (float*)d_out;

    char* ws = (char*)d_ws;
    float* w0 = (float*)ws;                                      // 64 floats
    float* s  = w0 + 64;                                         // 64 floats
    unsigned short* Wbf = (unsigned short*)(ws + 512);           // 4*9*192*192 bf16
    unsigned short* xbf = (unsigned short*)(ws + 512 + 2654208); // 4*66*66*192 bf16

    hipLaunchKernelGGL(pool_kernel, dim3(B_ * WN_), dim3(C_), 0, stream, x, conv1_w, dc_w, w0);
    hipLaunchKernelGGL(mlp_kernel, dim3(1), dim3(64), 0, stream, w0, dc_b, l1_w, l1_b, l2_w, l2_b, s);
    hipLaunchKernelGGL(weff_kernel, dim3(B_ * C_), dim3(C_), 0, stream, conv1_w, gk_w, gk_b, fusion_w, s, Wbf);
    hipLaunchKernelGGL(xpad_kernel, dim3(4 * 66 * 66 / 4), dim3(C_), 0, stream, x, xbf);
    hipLaunchKernelGGL(conv_kernel, dim3(R_, B_), dim3(256), 0, stream, xbf, Wbf, fusion_b, out);
}

// Round 3
// 126.551 us; speedup vs baseline: 1.5748x; 1.2098x over previous
//
#include <hip/hip_runtime.h>
#include <hip/hip_bf16.h>
#include <math.h>

#define B_  4
#define R_  64
#define C_  192
#define WN_ 16

// fragment-major A: xfrag[b][row0..65][kc0..5][px0..65][ci32]  (bf16)
//   short index = (b*66+row)*12672 + kc*2112 + px*32 + (ci%32), kc=ci/32
// fragment-major B: Wl[b][tap][kc][co][ci32] (bf16)
//   short index = (((b*9+tap)*6+kc)*192 + co)*32 + (ci%32)

typedef __attribute__((ext_vector_type(8))) short short8;
typedef __attribute__((ext_vector_type(4))) float floatx4;

static __device__ __forceinline__ unsigned short f2bf(float f) {
    union { float f; unsigned u; } v; v.f = f;
    unsigned r = v.u + 0x7fffu + ((v.u >> 16) & 1u);
    return (unsigned short)(r >> 16);
}

// ---------------------------------------------------------------------------
// Kernel 1 (fused prologue): blocks [0,64) = pool, [64,328) = xpad->fragment
// layout, [328,382) = conv1_w transpose to [tap][win][ci].
// ---------------------------------------------------------------------------
__global__ __launch_bounds__(256) void pre_kernel(
        const float* __restrict__ x,
        const float* __restrict__ conv1_w,
        const float* __restrict__ dc_w,
        float* __restrict__ w0,
        unsigned short* __restrict__ xfrag,
        float* __restrict__ cw_t) {
    __shared__ float part[3];
    int blk = blockIdx.x;
    int tid = threadIdx.x;

    if (blk < 64) {
        // ------- pool: per-(b,win) pooled depthwise mean dotted with dc_w ----
        int b = blk >> 4, win = blk & 15;
        int wr = win >> 2, wc = win & 3;
        if (tid < 192) {
            int c = tid;
            const float* xb = x + ((size_t)b * 4096) * C_ + c;
            float Wsum = 0.f, Rtop = 0.f, Rbot = 0.f, Cleft = 0.f, Cright = 0.f;
            float c00 = 0.f, c0F = 0.f, cF0 = 0.f, cFF = 0.f;
            for (int ph = 0; ph < 16; ++ph) {
                int h = wr * 16 + ph;
                #pragma unroll
                for (int pw = 0; pw < 16; ++pw) {
                    int w = wc * 16 + pw;
                    float v = xb[((size_t)(h * 64 + w)) * C_];
                    Wsum += v;
                    if (ph == 0)  { Rtop += v; if (pw == 0) c00 = v; if (pw == 15) c0F = v; }
                    if (ph == 15) { Rbot += v; if (pw == 0) cF0 = v; if (pw == 15) cFF = v; }
                    if (pw == 0)  Cleft  += v;
                    if (pw == 15) Cright += v;
                }
            }
            const float* kp = conv1_w + ((size_t)(win * C_ + c)) * 9;
            float pooled = 0.f;
            #pragma unroll
            for (int i = 0; i < 3; ++i) {
                #pragma unroll
                for (int j = 0; j < 3; ++j) {
                    int di = i - 1, dj = j - 1;
                    float S = Wsum;
                    if (di == -1) S -= Rbot;   else if (di == 1) S -= Rtop;
                    if (dj == -1) S -= Cright; else if (dj == 1) S -= Cleft;
                    if (di == -1 && dj == -1) S += cFF;
                    if (di == -1 && dj ==  1) S += cF0;
                    if (di ==  1 && dj == -1) S += c0F;
                    if (di ==  1 && dj ==  1) S += c00;
                    pooled += kp[i * 3 + j] * S;
                }
            }
            float val = (pooled * (1.f / 256.f)) * dc_w[win * C_ + c];
            for (int off = 32; off; off >>= 1) val += __shfl_down(val, off, 64);
            if ((tid & 63) == 0) part[tid >> 6] = val;
        }
        __syncthreads();
        if (tid == 0) w0[blk] = part[0] + part[1] + part[2];
    } else if (blk < 328) {
        // ------- xpad: fp32 x -> bf16 fragment-major padded rows -------------
        int rb = blk - 64;            // b*66 + row
        int b = rb / 66, row = rb % 66;
        int h = row - 1;
        unsigned short* orow = xfrag + (size_t)rb * 12672;
        for (int c = tid; c < 1584; c += 256) {       // 1584 chunks of 8 shorts
            int kc = c / 264;                          // 264 chunks per kc
            int rc = c - kc * 264;
            int px = rc >> 2;
            int cio = (rc & 3) * 8;
            int w = px - 1;
            short8 o;
            if (h >= 0 && h < 64 && w >= 0 && w < 64) {
                const float* src = x + (((size_t)b * 4096) + h * 64 + w) * C_ + kc * 32 + cio;
                const float4 v0 = *(const float4*)(src);
                const float4 v1 = *(const float4*)(src + 4);
                o[0] = (short)f2bf(v0.x); o[1] = (short)f2bf(v0.y);
                o[2] = (short)f2bf(v0.z); o[3] = (short)f2bf(v0.w);
                o[4] = (short)f2bf(v1.x); o[5] = (short)f2bf(v1.y);
                o[6] = (short)f2bf(v1.z); o[7] = (short)f2bf(v1.w);
            } else {
                o = (short8){0,0,0,0,0,0,0,0};
            }
            *(short8*)(orow + (size_t)c * 8) = o;
        }
    } else {
        // ------- transpose conv1_w (win*C,9) -> cw_t[tap][win][ci] -----------
        int base = (blk - 328) * 512 + tid * 2;       // 2 elems/thread, 27648 total
        #pragma unroll
        for (int e = 0; e < 2; ++e) {
            int o = base + e;
            int t = o / 3072;
            int r = o - t * 3072;                      // win*192+ci
            cw_t[o] = conv1_w[(size_t)r * 9 + t];
        }
    }
}

// ---------------------------------------------------------------------------
// Kernel 2: gates (tiny MLP, computed redundantly per block) + effective
// dense conv weights in fragment-major bf16 layout Wl[b][tap][kc][co][ci32].
// ---------------------------------------------------------------------------
__global__ __launch_bounds__(192) void weff_kernel(
        const float* __restrict__ cw_t,
        const float* __restrict__ gk_w,
        const float* __restrict__ gk_b,
        const float* __restrict__ fusion_w,
        const float* __restrict__ w0,
        const float* __restrict__ dc_b,
        const float* __restrict__ l1_w,
        const float* __restrict__ l1_b,
        const float* __restrict__ l2_w,
        const float* __restrict__ l2_b,
        unsigned short* __restrict__ Wl) {
    __shared__ float hbuf[64];
    __shared__ float s_sh[16];
    int blk = blockIdx.x;             // b*192 + co
    int b = blk / C_, co = blk % C_;
    int tid = threadIdx.x;            // 0..191

    // gates for batch b (one wave does the work, all blocks redundant)
    if (tid < 64) {
        float a = l1_b[tid];
        #pragma unroll
        for (int w = 0; w < 16; ++w)
            a += (w0[b * 16 + w] + dc_b[w]) * l1_w[tid * 16 + w];
        hbuf[tid] = 0.5f * a * (1.f + erff(a * 0.70710678118654752f));
    }
    __syncthreads();
    if (tid < 16) {
        float a2 = l2_b[tid];
        #pragma unroll
        for (int k = 0; k < 64; ++k) a2 += hbuf[k] * l2_w[tid * 64 + k];
        s_sh[tid] = 1.f / (1.f + expf(-a2));
    }
    __syncthreads();

    int ci = tid;
    float fg = fusion_w[(size_t)co * 3264 + 16 * C_ + ci];
    float acc[9];
    float g0 = fg * gk_b[0];
    #pragma unroll
    for (int t = 0; t < 9; ++t) acc[t] = g0;
    for (int w = 0; w < 16; ++w) {
        float coef = (fusion_w[(size_t)co * 3264 + w * C_ + ci] + fg * gk_w[w]) * s_sh[w];
        #pragma unroll
        for (int t = 0; t < 9; ++t)
            acc[t] += coef * cw_t[t * 3072 + w * C_ + ci];
    }
    #pragma unroll
    for (int t = 0; t < 9; ++t) {
        int kc = ci >> 5, cio = ci & 31;
        Wl[((((size_t)(b * 9 + t)) * 6 + kc) * C_ + co) * 32 + cio] = f2bf(acc[t]);
    }
}

// ---------------------------------------------------------------------------
// Kernel 3: dense 3x3 conv, register-tiled implicit GEMM, fragment-major
// global layouts -> every A/B fragment load is one contiguous 1 KB wave-load.
// Block = one row (64 px) x 192 co, 4 waves (wave = 64px x 48co, 4m x 3n,
// 12 MFMA per K-step from 7 loads). Depth-2 prefetch (3-slot ring).
// Grid linear 4h+b so each XCD's resident blocks share one batch (B slice
// 663 KB fits its L2).
// ---------------------------------------------------------------------------
__global__ __launch_bounds__(256, 1) void conv_kernel(
        const unsigned short* __restrict__ xfrag,
        const unsigned short* __restrict__ Wl,
        const float* __restrict__ fusion_b,
        float* __restrict__ out) {
    const int h = blockIdx.x >> 2;
    const int b = blockIdx.x & 3;
    const int tid = threadIdx.x;
    const int wv = tid >> 6;
    const int lane = tid & 63;
    const int lo = lane & 15, quad = lane >> 4;
    const int n0 = wv * 48;

    const short* xp = (const short*)xfrag;
    const short* wp = (const short*)Wl;

    int Abase[4], Bbase[3];
    #pragma unroll
    for (int mt = 0; mt < 4; ++mt)
        Abase[mt] = (b * 66 + h + 1) * 12672 + (mt * 16 + lo + 1) * 32 + quad * 8;
    #pragma unroll
    for (int nt = 0; nt < 3; ++nt)
        Bbase[nt] = (b * 9 * 6 * C_ + n0 + nt * 16 + lo) * 32 + quad * 8;

    floatx4 acc[4][3];
    #pragma unroll
    for (int mt = 0; mt < 4; ++mt)
        #pragma unroll
        for (int nt = 0; nt < 3; ++nt)
            acc[mt][nt] = (floatx4){0.f, 0.f, 0.f, 0.f};

    short8 Ab[3][4];
    short8 Bb[3][3];

    auto load_step = [&](int s, int slot) {
        const int tap = s / 6, kc = s % 6;
        const int dh = tap / 3 - 1, dw = tap % 3 - 1;
        const int aoff = dh * 12672 + dw * 32 + kc * 2112;
        const int boff = (tap * 6 + kc) * (C_ * 32);
        #pragma unroll
        for (int mt = 0; mt < 4; ++mt)
            Ab[slot][mt] = *(const short8*)(xp + Abase[mt] + aoff);
        #pragma unroll
        for (int nt = 0; nt < 3; ++nt)
            Bb[slot][nt] = *(const short8*)(wp + Bbase[nt] + boff);
    };

    load_step(0, 0);
    load_step(1, 1);

    #pragma unroll
    for (int step = 0; step < 54; ++step) {
        const int cur = step % 3;
        if (step + 2 < 54) load_step(step + 2, (step + 2) % 3);
        #pragma unroll
        for (int mt = 0; mt < 4; ++mt)
            #pragma unroll
            for (int nt = 0; nt < 3; ++nt)
                acc[mt][nt] = __builtin_amdgcn_mfma_f32_16x16x32_bf16(
                    Ab[cur][mt], Bb[cur][nt], acc[mt][nt], 0, 0, 0);
    }

    #pragma unroll
    for (int nt = 0; nt < 3; ++nt) {
        const int co = n0 + nt * 16 + lo;
        const float fb = fusion_b[co];
        #pragma unroll
        for (int mt = 0; mt < 4; ++mt) {
            #pragma unroll
            for (int r = 0; r < 4; ++r) {
                const int pix = mt * 16 + quad * 4 + r;
                out[(((size_t)b * 4096) + h * 64 + pix) * C_ + co] = acc[mt][nt][r] + fb;
            }
        }
    }
}

// ---------------------------------------------------------------------------
extern "C" void kernel_launch(void* const* d_in, const int* in_sizes, int n_in,
                              void* d_out, int out_size, void* d_ws, size_t ws_size,
                              hipStream_t stream) {
    const float* x        = (const float*)d_in[0];
    const float* conv1_w  = (const float*)d_in[1];
    const float* dc_w     = (const float*)d_in[2];
    const float* dc_b     = (const float*)d_in[3];
    const float* l1_w     = (const float*)d_in[4];
    const float* l1_b     = (const float*)d_in[5];
    const float* l2_w     = (const float*)d_in[6];
    const float* l2_b     = (const float*)d_in[7];
    const float* gk_w     = (const float*)d_in[8];
    const float* gk_b     = (const float*)d_in[9];
    const float* fusion_w = (const float*)d_in[10];
    const float* fusion_b = (const float*)d_in[11];
    float* out = (float*)d_out;

    char* ws = (char*)d_ws;
    float* w0   = (float*)ws;                                  // 64 floats
    float* cw_t = (float*)(ws + 512);                          // 27648 floats = 110,592 B
    unsigned short* Wl    = (unsigned short*)(ws + 512 + 110592);            // 2,654,208 B
    unsigned short* xfrag = (unsigned short*)(ws + 512 + 110592 + 2654208);  // 6,690,816 B
    // total ~9.46 MB

    hipLaunchKernelGGL(pre_kernel, dim3(382), dim3(256), 0, stream,
                       x, conv1_w, dc_w, w0, xfrag, cw_t);
    hipLaunchKernelGGL(weff_kernel, dim3(B_ * C_), dim3(192), 0, stream,
                       cw_t, gk_w, gk_b, fusion_w, w0, dc_b, l1_w, l1_b, l2_w, l2_b, Wl);
    hipLaunchKernelGGL(conv_kernel, dim3(R_ * B_), dim3(256), 0, stream,
                       xfrag, Wl, fusion_b, out);
}

// Round 4
// 120.615 us; speedup vs baseline: 1.6523x; 1.0492x over previous
//
#include <hip/hip_runtime.h>
#include <hip/hip_bf16.h>
#include <math.h>

#define B_  4
#define R_  64
#define C_  192
#define WN_ 16

// B (weights) fragment-major: Wl[b][tap][kc][co][ci32] (bf16)
//   short index = (((b*9+tap)*6+kc)*192 + co)*32 + (ci%32)
// A (input) staged per-block into LDS: Asm[r0..2][kcl0..2][px0..65][ci32] bf16

typedef __attribute__((ext_vector_type(8))) short short8;
typedef __attribute__((ext_vector_type(4))) float floatx4;

static __device__ __forceinline__ unsigned short f2bf(float f) {
    union { float f; unsigned u; } v; v.f = f;
    unsigned r = v.u + 0x7fffu + ((v.u >> 16) & 1u);
    return (unsigned short)(r >> 16);
}

// ---------------------------------------------------------------------------
// Kernel 1: blocks [0,256) = pool partials (one quarter-window each),
// blocks [256,310) = conv1_w transpose to cw_t[tap][win][ci].
// Quarter-split pool: each quarter owns only its physical edge rows; with
// non-owned edge aggregates = 0 the tap-clipping formula is additive.
// ---------------------------------------------------------------------------
__global__ __launch_bounds__(256) void pre_kernel(
        const float* __restrict__ x,
        const float* __restrict__ conv1_w,
        const float* __restrict__ dc_w,
        float* __restrict__ w0p,
        float* __restrict__ cw_t) {
    __shared__ float part[3];
    int blk = blockIdx.x;
    int tid = threadIdx.x;

    if (blk < 256) {
        int b = blk >> 6, rest = blk & 63, win = rest >> 2, q = rest & 3;
        int wr = win >> 2, wc = win & 3;
        if (tid < 192) {
            const float* xb = x + ((size_t)b * 4096) * C_ + tid;
            float Wsum = 0.f, Rtop = 0.f, Rbot = 0.f, Cleft = 0.f, Cright = 0.f;
            float c00 = 0.f, c0F = 0.f, cF0 = 0.f, cFF = 0.f;
            #pragma unroll
            for (int pr = 0; pr < 4; ++pr) {
                int h = wr * 16 + q * 4 + pr;
                #pragma unroll
                for (int pw = 0; pw < 16; ++pw) {
                    int w = wc * 16 + pw;
                    float v = xb[(size_t)(h * 64 + w) * C_];
                    Wsum += v;
                    if (q == 0 && pr == 0) { Rtop += v; if (pw == 0) c00 = v; if (pw == 15) c0F = v; }
                    if (q == 3 && pr == 3) { Rbot += v; if (pw == 0) cF0 = v; if (pw == 15) cFF = v; }
                    if (pw == 0)  Cleft  += v;
                    if (pw == 15) Cright += v;
                }
            }
            const float* kp = conv1_w + ((size_t)(win * C_ + tid)) * 9;
            float pooled = 0.f;
            #pragma unroll
            for (int i = 0; i < 3; ++i) {
                #pragma unroll
                for (int j = 0; j < 3; ++j) {
                    int di = i - 1, dj = j - 1;
                    float S = Wsum;
                    if (di == -1) S -= Rbot;   else if (di == 1) S -= Rtop;
                    if (dj == -1) S -= Cright; else if (dj == 1) S -= Cleft;
                    if (di == -1 && dj == -1) S += cFF;
                    if (di == -1 && dj ==  1) S += cF0;
                    if (di ==  1 && dj == -1) S += c0F;
                    if (di ==  1 && dj ==  1) S += c00;
                    pooled += kp[i * 3 + j] * S;
                }
            }
            float val = (pooled * (1.f / 256.f)) * dc_w[win * C_ + tid];
            for (int off = 32; off; off >>= 1) val += __shfl_down(val, off, 64);
            if ((tid & 63) == 0) part[tid >> 6] = val;
        }
        __syncthreads();
        if (tid == 0) w0p[blk] = part[0] + part[1] + part[2];
    } else {
        int basei = (blk - 256) * 512 + tid * 2;   // 54*512 = 27648 elements
        #pragma unroll
        for (int e = 0; e < 2; ++e) {
            int o = basei + e;
            int t = o / 3072;
            int r = o - t * 3072;                  // win*192+ci
            cw_t[o] = conv1_w[(size_t)r * 9 + t];
        }
    }
}

// ---------------------------------------------------------------------------
// Kernel 2: gates (tiny MLP, redundant per block) + effective dense conv
// weights in fragment-major bf16 layout Wl[b][tap][kc][co][ci32].
// ---------------------------------------------------------------------------
__global__ __launch_bounds__(192) void weff_kernel(
        const float* __restrict__ cw_t,
        const float* __restrict__ gk_w,
        const float* __restrict__ gk_b,
        const float* __restrict__ fusion_w,
        const float* __restrict__ w0p,
        const float* __restrict__ dc_b,
        const float* __restrict__ l1_w,
        const float* __restrict__ l1_b,
        const float* __restrict__ l2_w,
        const float* __restrict__ l2_b,
        unsigned short* __restrict__ Wl) {
    __shared__ float hbuf[64];
    __shared__ float s_sh[16];
    int blk = blockIdx.x;             // b*192 + co
    int b = blk / C_, co = blk % C_;
    int tid = threadIdx.x;            // 0..191

    if (tid < 64) {
        float a = l1_b[tid];
        #pragma unroll
        for (int w = 0; w < 16; ++w) {
            float w0 = w0p[b * 64 + w * 4 + 0] + w0p[b * 64 + w * 4 + 1]
                     + w0p[b * 64 + w * 4 + 2] + w0p[b * 64 + w * 4 + 3];
            a += (w0 + dc_b[w]) * l1_w[tid * 16 + w];
        }
        hbuf[tid] = 0.5f * a * (1.f + erff(a * 0.70710678118654752f));
    }
    __syncthreads();
    if (tid < 16) {
        float a2 = l2_b[tid];
        #pragma unroll
        for (int k = 0; k < 64; ++k) a2 += hbuf[k] * l2_w[tid * 64 + k];
        s_sh[tid] = 1.f / (1.f + expf(-a2));
    }
    __syncthreads();

    int ci = tid;
    float fg = fusion_w[(size_t)co * 3264 + 16 * C_ + ci];
    float acc[9];
    float g0 = fg * gk_b[0];
    #pragma unroll
    for (int t = 0; t < 9; ++t) acc[t] = g0;
    for (int w = 0; w < 16; ++w) {
        float coef = (fusion_w[(size_t)co * 3264 + w * C_ + ci] + fg * gk_w[w]) * s_sh[w];
        #pragma unroll
        for (int t = 0; t < 9; ++t)
            acc[t] += coef * cw_t[t * 3072 + w * C_ + ci];
    }
    #pragma unroll
    for (int t = 0; t < 9; ++t) {
        int kc = ci >> 5, cio = ci & 31;
        Wl[((((size_t)(b * 9 + t)) * 6 + kc) * C_ + co) * 32 + cio] = f2bf(acc[t]);
    }
}

// ---------------------------------------------------------------------------
// Kernel 3: dense 3x3 conv, implicit GEMM. One block per (b,h): 512 threads =
// 8 waves (2 waves/SIMD for MFMA pipelining). Wave = 32 px x 48 co (2m x 3n,
// 6 MFMA / 5 loads per K-step). A is staged from fp32 x into LDS bf16
// fragment layout in two kc-phases (38 KB LDS); ds_read_b128 fragments are
// contiguous 1 KB, conflict-free. B read from global (L2-resident per XCD via
// swizzle), depth-2 prefetch ring. Grid swizzle: each XCD owns 32 consecutive
// rows of ONE batch -> B slice 663 KB + ~34 x-rows fit its 4 MB L2.
// ---------------------------------------------------------------------------
__global__ __launch_bounds__(512, 2) void conv_kernel(
        const float* __restrict__ x,
        const unsigned short* __restrict__ Wl,
        const float* __restrict__ fusion_b,
        float* __restrict__ out) {
    __shared__ unsigned short Asm[3 * 3 * 66 * 32];   // 38,016 B
    const int n = blockIdx.x;
    const int g = (n & 7) * 32 + (n >> 3);
    const int b = g >> 6, h = g & 63;
    const int tid = threadIdx.x;
    const int wv = tid >> 6, lane = tid & 63;
    const int lo = lane & 15, quad = lane >> 4;
    const int cs = wv >> 1, pxh = wv & 1;
    const int n0 = cs * 48;

    const short* wp = (const short*)Wl;
    int Bbase[3];
    #pragma unroll
    for (int nt = 0; nt < 3; ++nt)
        Bbase[nt] = (b * 54 * C_ + n0 + nt * 16 + lo) * 32 + quad * 8;
    int Alds[2];
    #pragma unroll
    for (int mt = 0; mt < 2; ++mt)
        Alds[mt] = (pxh * 32 + mt * 16 + lo + 1) * 32 + quad * 8;

    floatx4 acc[2][3];
    #pragma unroll
    for (int mt = 0; mt < 2; ++mt)
        #pragma unroll
        for (int nt = 0; nt < 3; ++nt)
            acc[mt][nt] = (floatx4){0.f, 0.f, 0.f, 0.f};

    #pragma unroll
    for (int ph = 0; ph < 2; ++ph) {
        const int kc0 = ph * 3;
        // ---- stage 3 rows x 3 kc-chunks of x into LDS (bf16 fragment layout)
        #pragma unroll
        for (int r = 0; r < 3; ++r) {
            int hr = h - 1 + r;
            unsigned short* Lr = Asm + r * (3 * 66 * 32);
            if (hr >= 0 && hr < 64) {
                const float* src = x + ((size_t)(b * 4096 + hr * 64)) * C_ + kc0 * 32;
                for (int c = tid; c < 768; c += 512) {
                    int px = c / 12, sub = c % 12;
                    int kcl = sub >> 2, ci0 = (sub & 3) * 8;
                    const float* p = src + px * C_ + kcl * 32 + ci0;
                    float4 v0 = *(const float4*)p;
                    float4 v1 = *(const float4*)(p + 4);
                    short8 o;
                    o[0] = (short)f2bf(v0.x); o[1] = (short)f2bf(v0.y);
                    o[2] = (short)f2bf(v0.z); o[3] = (short)f2bf(v0.w);
                    o[4] = (short)f2bf(v1.x); o[5] = (short)f2bf(v1.y);
                    o[6] = (short)f2bf(v1.z); o[7] = (short)f2bf(v1.w);
                    *(short8*)(Lr + (kcl * 66 + px + 1) * 32 + ci0) = o;
                }
            } else {
                for (int c = tid; c < 792; c += 512)
                    *(short8*)(Lr + c * 8) = (short8){0, 0, 0, 0, 0, 0, 0, 0};
            }
        }
        // zero the px=0 / px=65 halo columns
        if (tid < 72) {
            int loc = tid >> 2, j = tid & 3;
            int r = loc / 6, rem = loc % 6, kcl = rem >> 1, px = (rem & 1) * 65;
            *(short8*)(Asm + ((r * 3 + kcl) * 66 + px) * 32 + j * 8) =
                (short8){0, 0, 0, 0, 0, 0, 0, 0};
        }
        __syncthreads();

        // ---- 27 K-steps: taps 0..8 x kcl 0..2
        short8 Bb[3][3], Ab[2][2];
        auto loadB = [&](int t27, int slot) {
            int tap = t27 / 3, kcl = t27 % 3;
            int s = tap * 6 + kc0 + kcl;
            #pragma unroll
            for (int nt = 0; nt < 3; ++nt)
                Bb[slot][nt] = *(const short8*)(wp + Bbase[nt] + s * (C_ * 32));
        };
        auto loadA = [&](int t27, int slot) {
            int tap = t27 / 3, kcl = t27 % 3;
            int dh = tap / 3, dw = tap % 3 - 1;
            int base = ((dh * 3 + kcl) * 66 + dw) * 32;
            #pragma unroll
            for (int mt = 0; mt < 2; ++mt)
                Ab[slot][mt] = *(const short8*)((const short*)Asm + base + Alds[mt]);
        };
        loadB(0, 0); loadB(1, 1); loadA(0, 0);
        #pragma unroll
        for (int t = 0; t < 27; ++t) {
            const int bc = t % 3, ac = t & 1;
            if (t + 2 < 27) loadB(t + 2, (t + 2) % 3);
            if (t + 1 < 27) loadA(t + 1, ac ^ 1);
            #pragma unroll
            for (int mt = 0; mt < 2; ++mt)
                #pragma unroll
                for (int nt = 0; nt < 3; ++nt)
                    acc[mt][nt] = __builtin_amdgcn_mfma_f32_16x16x32_bf16(
                        Ab[ac][mt], Bb[bc][nt], acc[mt][nt], 0, 0, 0);
        }
        __syncthreads();   // LDS reads done before next phase restages
    }

    // ---- epilogue
    #pragma unroll
    for (int nt = 0; nt < 3; ++nt) {
        const int co = n0 + nt * 16 + lo;
        const float fb = fusion_b[co];
        #pragma unroll
        for (int mt = 0; mt < 2; ++mt) {
            #pragma unroll
            for (int r = 0; r < 4; ++r) {
                const int px = pxh * 32 + mt * 16 + quad * 4 + r;
                out[((size_t)(b * 4096 + h * 64 + px)) * C_ + co] = acc[mt][nt][r] + fb;
            }
        }
    }
}

// ---------------------------------------------------------------------------
extern "C" void kernel_launch(void* const* d_in, const int* in_sizes, int n_in,
                              void* d_out, int out_size, void* d_ws, size_t ws_size,
                              hipStream_t stream) {
    const float* x        = (const float*)d_in[0];
    const float* conv1_w  = (const float*)d_in[1];
    const float* dc_w     = (const float*)d_in[2];
    const float* dc_b     = (const float*)d_in[3];
    const float* l1_w     = (const float*)d_in[4];
    const float* l1_b     = (const float*)d_in[5];
    const float* l2_w     = (const float*)d_in[6];
    const float* l2_b     = (const float*)d_in[7];
    const float* gk_w     = (const float*)d_in[8];
    const float* gk_b     = (const float*)d_in[9];
    const float* fusion_w = (const float*)d_in[10];
    const float* fusion_b = (const float*)d_in[11];
    float* out = (float*)d_out;

    char* ws = (char*)d_ws;
    float* w0p  = (float*)ws;                                  // 256 floats
    float* cw_t = (float*)(ws + 1024);                         // 27648 floats
    unsigned short* Wl = (unsigned short*)(ws + 1024 + 110592); // 2,654,208 B
    // total ws use ~2.8 MB

    hipLaunchKernelGGL(pre_kernel, dim3(310), dim3(256), 0, stream,
                       x, conv1_w, dc_w, w0p, cw_t);
    hipLaunchKernelGGL(weff_kernel, dim3(B_ * C_), dim3(192), 0, stream,
                       cw_t, gk_w, gk_b, fusion_w, w0p, dc_b, l1_w, l1_b, l2_w, l2_b, Wl);
    hipLaunchKernelGGL(conv_kernel, dim3(256), dim3(512), 0, stream,
                       x, Wl, fusion_b, out);
}

// Round 5
// 118.648 us; speedup vs baseline: 1.6797x; 1.0166x over previous
//
#include <hip/hip_runtime.h>
#include <hip/hip_bf16.h>
#include <math.h>

#define B_  4
#define R_  64
#define C_  192
#define WN_ 16

// B (weights) fragment-major: Wl[b][tap][kc][co][ci32] (bf16)
//   short index = (((b*9+tap)*6+kc)*192 + co)*32 + (ci%32)
// A (input) staged per-block into LDS: Asm[r0..2][kcl0..2][px0..65][ci32] bf16

typedef __attribute__((ext_vector_type(8))) short short8;
typedef __attribute__((ext_vector_type(4))) float floatx4;

static __device__ __forceinline__ unsigned short f2bf(float f) {
    union { float f; unsigned u; } v; v.f = f;
    unsigned r = v.u + 0x7fffu + ((v.u >> 16) & 1u);
    return (unsigned short)(r >> 16);
}

// ---------------------------------------------------------------------------
// Kernel 1: blocks [0,256) = pool partials (one quarter-window each),
// blocks [256,310) = conv1_w transpose to cw_t[tap][win][ci].
// ---------------------------------------------------------------------------
__global__ __launch_bounds__(256) void pre_kernel(
        const float* __restrict__ x,
        const float* __restrict__ conv1_w,
        const float* __restrict__ dc_w,
        float* __restrict__ w0p,
        float* __restrict__ cw_t) {
    __shared__ float part[3];
    int blk = blockIdx.x;
    int tid = threadIdx.x;

    if (blk < 256) {
        int b = blk >> 6, rest = blk & 63, win = rest >> 2, q = rest & 3;
        int wr = win >> 2, wc = win & 3;
        if (tid < 192) {
            const float* xb = x + ((size_t)b * 4096) * C_ + tid;
            float Wsum = 0.f, Rtop = 0.f, Rbot = 0.f, Cleft = 0.f, Cright = 0.f;
            float c00 = 0.f, c0F = 0.f, cF0 = 0.f, cFF = 0.f;
            #pragma unroll
            for (int pr = 0; pr < 4; ++pr) {
                int h = wr * 16 + q * 4 + pr;
                #pragma unroll
                for (int pw = 0; pw < 16; ++pw) {
                    int w = wc * 16 + pw;
                    float v = xb[(size_t)(h * 64 + w) * C_];
                    Wsum += v;
                    if (q == 0 && pr == 0) { Rtop += v; if (pw == 0) c00 = v; if (pw == 15) c0F = v; }
                    if (q == 3 && pr == 3) { Rbot += v; if (pw == 0) cF0 = v; if (pw == 15) cFF = v; }
                    if (pw == 0)  Cleft  += v;
                    if (pw == 15) Cright += v;
                }
            }
            const float* kp = conv1_w + ((size_t)(win * C_ + tid)) * 9;
            float pooled = 0.f;
            #pragma unroll
            for (int i = 0; i < 3; ++i) {
                #pragma unroll
                for (int j = 0; j < 3; ++j) {
                    int di = i - 1, dj = j - 1;
                    float S = Wsum;
                    if (di == -1) S -= Rbot;   else if (di == 1) S -= Rtop;
                    if (dj == -1) S -= Cright; else if (dj == 1) S -= Cleft;
                    if (di == -1 && dj == -1) S += cFF;
                    if (di == -1 && dj ==  1) S += cF0;
                    if (di ==  1 && dj == -1) S += c0F;
                    if (di ==  1 && dj ==  1) S += c00;
                    pooled += kp[i * 3 + j] * S;
                }
            }
            float val = (pooled * (1.f / 256.f)) * dc_w[win * C_ + tid];
            for (int off = 32; off; off >>= 1) val += __shfl_down(val, off, 64);
            if ((tid & 63) == 0) part[tid >> 6] = val;
        }
        __syncthreads();
        if (tid == 0) w0p[blk] = part[0] + part[1] + part[2];
    } else {
        int basei = (blk - 256) * 512 + tid * 2;   // 54*512 = 27648 elements
        #pragma unroll
        for (int e = 0; e < 2; ++e) {
            int o = basei + e;
            int t = o / 3072;
            int r = o - t * 3072;                  // win*192+ci
            cw_t[o] = conv1_w[(size_t)r * 9 + t];
        }
    }
}

// ---------------------------------------------------------------------------
// Kernel 2: gates (tiny MLP, redundant per block) + effective dense conv
// weights in fragment-major bf16 layout Wl[b][tap][kc][co][ci32].
// ---------------------------------------------------------------------------
__global__ __launch_bounds__(192) void weff_kernel(
        const float* __restrict__ cw_t,
        const float* __restrict__ gk_w,
        const float* __restrict__ gk_b,
        const float* __restrict__ fusion_w,
        const float* __restrict__ w0p,
        const float* __restrict__ dc_b,
        const float* __restrict__ l1_w,
        const float* __restrict__ l1_b,
        const float* __restrict__ l2_w,
        const float* __restrict__ l2_b,
        unsigned short* __restrict__ Wl) {
    __shared__ float hbuf[64];
    __shared__ float s_sh[16];
    int blk = blockIdx.x;             // b*192 + co
    int b = blk / C_, co = blk % C_;
    int tid = threadIdx.x;            // 0..191

    if (tid < 64) {
        float a = l1_b[tid];
        #pragma unroll
        for (int w = 0; w < 16; ++w) {
            float w0 = w0p[b * 64 + w * 4 + 0] + w0p[b * 64 + w * 4 + 1]
                     + w0p[b * 64 + w * 4 + 2] + w0p[b * 64 + w * 4 + 3];
            a += (w0 + dc_b[w]) * l1_w[tid * 16 + w];
        }
        hbuf[tid] = 0.5f * a * (1.f + erff(a * 0.70710678118654752f));
    }
    __syncthreads();
    if (tid < 16) {
        float a2 = l2_b[tid];
        #pragma unroll
        for (int k = 0; k < 64; ++k) a2 += hbuf[k] * l2_w[tid * 64 + k];
        s_sh[tid] = 1.f / (1.f + expf(-a2));
    }
    __syncthreads();

    int ci = tid;
    float fg = fusion_w[(size_t)co * 3264 + 16 * C_ + ci];
    float acc[9];
    float g0 = fg * gk_b[0];
    #pragma unroll
    for (int t = 0; t < 9; ++t) acc[t] = g0;
    for (int w = 0; w < 16; ++w) {
        float coef = (fusion_w[(size_t)co * 3264 + w * C_ + ci] + fg * gk_w[w]) * s_sh[w];
        #pragma unroll
        for (int t = 0; t < 9; ++t)
            acc[t] += coef * cw_t[t * 3072 + w * C_ + ci];
    }
    #pragma unroll
    for (int t = 0; t < 9; ++t) {
        int kc = ci >> 5, cio = ci & 31;
        Wl[((((size_t)(b * 9 + t)) * 6 + kc) * C_ + co) * 32 + cio] = f2bf(acc[t]);
    }
}

// ---------------------------------------------------------------------------
// Kernel 3 (v3): dense 3x3 conv, implicit GEMM. 256 threads = 4 waves; block
// = one row (M=64px) x 192 co. Wave = 64px x 48co: m=4 x n=3 -> 12 MFMA per
// (4 LDS-A + 3 global-B) loads. Doubling m vs v2 halves B-issue bytes per
// MFMA (B/MFMA = 1/m KB): per-CU per step now 12 KB B (~96cyc) + 16 KB A-LDS
// (~125cyc) vs 58cyc MFMA. A staged from fp32 x into LDS bf16 fragment
// layout, two kc-phases (38 KB). Depth-2 B ring, depth-1 A. Grid 256 = 1
// block/CU; XCD swizzle: 2 XCDs per batch -> Wl slice 663 KB in each L2.
// ---------------------------------------------------------------------------
__global__ __launch_bounds__(256, 1) void conv_kernel(
        const float* __restrict__ x,
        const unsigned short* __restrict__ Wl,
        const float* __restrict__ fusion_b,
        float* __restrict__ out) {
    __shared__ unsigned short Asm[3 * 3 * 66 * 32];   // 38,016 B
    const int n = blockIdx.x;
    const int g = (n & 7) * 32 + (n >> 3);
    const int b = g >> 6, h = g & 63;
    const int tid = threadIdx.x;
    const int wv = tid >> 6, lane = tid & 63;
    const int lo = lane & 15, quad = lane >> 4;
    const int n0 = wv * 48;

    const short* wp = (const short*)Wl;
    int Bbase[3];
    #pragma unroll
    for (int nt = 0; nt < 3; ++nt)
        Bbase[nt] = (b * 54 * C_ + n0 + nt * 16 + lo) * 32 + quad * 8;
    int Alds[4];
    #pragma unroll
    for (int mt = 0; mt < 4; ++mt)
        Alds[mt] = (mt * 16 + lo + 1) * 32 + quad * 8;

    floatx4 acc[4][3];
    #pragma unroll
    for (int mt = 0; mt < 4; ++mt)
        #pragma unroll
        for (int nt = 0; nt < 3; ++nt)
            acc[mt][nt] = (floatx4){0.f, 0.f, 0.f, 0.f};

    #pragma unroll
    for (int ph = 0; ph < 2; ++ph) {
        const int kc0 = ph * 3;
        // ---- stage 3 rows x 3 kc-chunks of x into LDS (bf16 fragment layout)
        #pragma unroll
        for (int r = 0; r < 3; ++r) {
            int hr = h - 1 + r;
            unsigned short* Lr = Asm + r * (3 * 66 * 32);
            if (hr >= 0 && hr < 64) {
                const float* src = x + ((size_t)(b * 4096 + hr * 64)) * C_ + kc0 * 32;
                #pragma unroll
                for (int it = 0; it < 3; ++it) {
                    int c = tid + it * 256;               // < 768
                    int px = c / 12, sub = c % 12;
                    int kcl = sub >> 2, ci0 = (sub & 3) * 8;
                    const float* p = src + px * C_ + kcl * 32 + ci0;
                    float4 v0 = *(const float4*)p;
                    float4 v1 = *(const float4*)(p + 4);
                    short8 o;
                    o[0] = (short)f2bf(v0.x); o[1] = (short)f2bf(v0.y);
                    o[2] = (short)f2bf(v0.z); o[3] = (short)f2bf(v0.w);
                    o[4] = (short)f2bf(v1.x); o[5] = (short)f2bf(v1.y);
                    o[6] = (short)f2bf(v1.z); o[7] = (short)f2bf(v1.w);
                    *(short8*)(Lr + (kcl * 66 + px + 1) * 32 + ci0) = o;
                }
            } else {
                for (int c = tid; c < 792; c += 256)
                    *(short8*)(Lr + c * 8) = (short8){0, 0, 0, 0, 0, 0, 0, 0};
            }
        }
        // zero the px=0 / px=65 halo columns (3 rows x 3 kcl x 2 sides x 4 j)
        if (tid < 72) {
            int loc = tid >> 2, j = tid & 3;
            int r = loc / 6, rem = loc % 6, kcl = rem >> 1, px = (rem & 1) * 65;
            *(short8*)(Asm + ((r * 3 + kcl) * 66 + px) * 32 + j * 8) =
                (short8){0, 0, 0, 0, 0, 0, 0, 0};
        }
        __syncthreads();

        // ---- 27 K-steps: taps 0..8 x kcl 0..2
        short8 Bb[3][3], Ab[2][4];
        auto loadB = [&](int t27, int slot) {
            int tap = t27 / 3, kcl = t27 % 3;
            int s = tap * 6 + kc0 + kcl;
            #pragma unroll
            for (int nt = 0; nt < 3; ++nt)
                Bb[slot][nt] = *(const short8*)(wp + Bbase[nt] + s * (C_ * 32));
        };
        auto loadA = [&](int t27, int slot) {
            int tap = t27 / 3, kcl = t27 % 3;
            int dh = tap / 3, dw = tap % 3 - 1;
            int base = ((dh * 3 + kcl) * 66 + dw) * 32;
            #pragma unroll
            for (int mt = 0; mt < 4; ++mt)
                Ab[slot][mt] = *(const short8*)((const short*)Asm + base + Alds[mt]);
        };
        loadB(0, 0); loadB(1, 1); loadA(0, 0);
        #pragma unroll
        for (int t = 0; t < 27; ++t) {
            const int bc = t % 3, ac = t & 1;
            if (t + 2 < 27) loadB(t + 2, (t + 2) % 3);
            if (t + 1 < 27) loadA(t + 1, ac ^ 1);
            #pragma unroll
            for (int mt = 0; mt < 4; ++mt)
                #pragma unroll
                for (int nt = 0; nt < 3; ++nt)
                    acc[mt][nt] = __builtin_amdgcn_mfma_f32_16x16x32_bf16(
                        Ab[ac][mt], Bb[bc][nt], acc[mt][nt], 0, 0, 0);
        }
        __syncthreads();   // LDS reads done before next phase restages
    }

    // ---- epilogue
    #pragma unroll
    for (int nt = 0; nt < 3; ++nt) {
        const int co = n0 + nt * 16 + lo;
        const float fb = fusion_b[co];
        #pragma unroll
        for (int mt = 0; mt < 4; ++mt) {
            #pragma unroll
            for (int r = 0; r < 4; ++r) {
                const int px = mt * 16 + quad * 4 + r;
                out[((size_t)(b * 4096 + h * 64 + px)) * C_ + co] = acc[mt][nt][r] + fb;
            }
        }
    }
}

// ---------------------------------------------------------------------------
extern "C" void kernel_launch(void* const* d_in, const int* in_sizes, int n_in,
                              void* d_out, int out_size, void* d_ws, size_t ws_size,
                              hipStream_t stream) {
    const float* x        = (const float*)d_in[0];
    const float* conv1_w  = (const float*)d_in[1];
    const float* dc_w     = (const float*)d_in[2];
    const float* dc_b     = (const float*)d_in[3];
    const float* l1_w     = (const float*)d_in[4];
    const float* l1_b     = (const float*)d_in[5];
    const float* l2_w     = (const float*)d_in[6];
    const float* l2_b     = (const float*)d_in[7];
    const float* gk_w     = (const float*)d_in[8];
    const float* gk_b     = (const float*)d_in[9];
    const float* fusion_w = (const float*)d_in[10];
    const float* fusion_b = (const float*)d_in[11];
    float* out = (float*)d_out;

    char* ws = (char*)d_ws;
    float* w0p  = (float*)ws;                                  // 256 floats
    float* cw_t = (float*)(ws + 1024);                         // 27648 floats
    unsigned short* Wl = (unsigned short*)(ws + 1024 + 110592); // 2,654,208 B

    hipLaunchKernelGGL(pre_kernel, dim3(310), dim3(256), 0, stream,
                       x, conv1_w, dc_w, w0p, cw_t);
    hipLaunchKernelGGL(weff_kernel, dim3(B_ * C_), dim3(192), 0, stream,
                       cw_t, gk_w, gk_b, fusion_w, w0p, dc_b, l1_w, l1_b, l2_w, l2_b, Wl);
    hipLaunchKernelGGL(conv_kernel, dim3(256), dim3(256), 0, stream,
                       x, Wl, fusion_b, out);
}